// Round 2
// baseline (675.130 us; speedup 1.0000x reference)
//
#include <hip/hip_runtime.h>

typedef unsigned short u16;
typedef __bf16 bf16x8 __attribute__((ext_vector_type(8)));
typedef float f32x4v __attribute__((ext_vector_type(4)));
typedef u16 u16x8 __attribute__((ext_vector_type(8)));

__device__ __forceinline__ u16 f2bf(float f) {
  union { float f; unsigned u; } v; v.f = f;
  unsigned r = v.u + 0x7fffu + ((v.u >> 16) & 1u);  // round-to-nearest-even
  return (u16)(r >> 16);
}
__device__ __forceinline__ float bf2f(u16 h) {
  union { unsigned u; float f; } v; v.u = ((unsigned)h) << 16;
  return v.f;
}

#define G2L16(g, l)                                                            \
  __builtin_amdgcn_global_load_lds((__attribute__((address_space(1))) void*)(g), \
                                   (__attribute__((address_space(3))) void*)(l), 16, 0, 0)

// ---------------- merged transpose + fp32->bf16 for W1 and W2 ----------------
// W1 (2048x4096) -> W1T (4096x2048); W2 (4096x2048) -> W2T (2048x4096)
__global__ __launch_bounds__(256) void k_transpose2(const float* __restrict__ W1,
                                                    u16* __restrict__ W1T,
                                                    const float* __restrict__ W2,
                                                    u16* __restrict__ W2T) {
  __shared__ float tile[32][33];
  int bid = blockIdx.x;
  const float* in;
  u16* out;
  int R, C, bx, by;
  if (bid < 8192) {            // W1: tiles 128 x 64
    in = W1; out = W1T; R = 2048; C = 4096;
    bx = bid & 127; by = bid >> 7;
  } else {                     // W2: tiles 64 x 128
    bid -= 8192;
    in = W2; out = W2T; R = 4096; C = 2048;
    bx = bid & 63; by = bid >> 6;
  }
  const int c0 = bx * 32, r0 = by * 32;
  const int tx = threadIdx.x & 31, ty = threadIdx.x >> 5;
#pragma unroll
  for (int i = 0; i < 4; ++i) {
    int r = ty + i * 8;
    tile[r][tx] = in[(size_t)(r0 + r) * C + c0 + tx];
  }
  __syncthreads();
#pragma unroll
  for (int i = 0; i < 4; ++i) {
    int r = ty + i * 8;
    out[(size_t)(c0 + r) * R + r0 + tx] = f2bf(tile[tx][r]);
  }
}

// ---------------- PQ table (split-K, atomicAdd into zeroed PQ) ---------------
// pq[(e*2+p)][c][n] = sum_k x1[c][k] * We[e][p*1024+k][n]
__global__ __launch_bounds__(256) void k_pq(const float* __restrict__ x1,
                                            const float* __restrict__ We,
                                            float* __restrict__ pq) {
  const int n0 = blockIdx.x * 64;
  const int ep = blockIdx.y;  // e*2+p
  const int e = ep >> 1, p = ep & 1;
  const int ks = blockIdx.z * 128;
  __shared__ float As[64][33];
  __shared__ float Bs[32][68];
  const int t = threadIdx.x;
  const int tx = t & 15, ty = t >> 4;
  float acc[4][4] = {};
  const float* wbase = We + (size_t)e * 2048 * 1024 + (size_t)p * 1024 * 1024;
  for (int k0 = ks; k0 < ks + 128; k0 += 32) {
#pragma unroll
    for (int i = 0; i < 8; ++i) {
      int idx = t + i * 256;
      As[idx >> 5][idx & 31] = x1[(size_t)(idx >> 5) * 1024 + k0 + (idx & 31)];
    }
#pragma unroll
    for (int i = 0; i < 8; ++i) {
      int idx = t + i * 256;
      Bs[idx >> 6][idx & 63] = wbase[(size_t)(k0 + (idx >> 6)) * 1024 + n0 + (idx & 63)];
    }
    __syncthreads();
#pragma unroll
    for (int kk = 0; kk < 32; ++kk) {
      float av[4];
#pragma unroll
      for (int i = 0; i < 4; ++i) av[i] = As[ty * 4 + i][kk];
      f32x4v bv = *(const f32x4v*)&Bs[kk][tx * 4];
#pragma unroll
      for (int i = 0; i < 4; ++i)
#pragma unroll
        for (int j = 0; j < 4; ++j) acc[i][j] += av[i] * bv[j];
    }
    __syncthreads();
  }
#pragma unroll
  for (int i = 0; i < 4; ++i) {
    float* dst = pq + ((size_t)ep * 64 + ty * 4 + i) * 1024 + n0 + tx * 4;
#pragma unroll
    for (int j = 0; j < 4; ++j) atomicAdd(&dst[j], acc[i][j]);
  }
}

// ---------------- build Y (8192 x 2048, bf16): [relu(P+Q+be) | x2] ----------
__global__ __launch_bounds__(256) void k_build_y(const float* __restrict__ pq,
                                                 const float* __restrict__ x2,
                                                 const float* __restrict__ be,
                                                 const int* __restrict__ cp,
                                                 const int* __restrict__ vis,
                                                 u16* __restrict__ Y) {
  const int b = blockIdx.x;
  const int t = threadIdx.x;
  const int e = vis[b];
  u16x8 o;
  if (t < 128) {
    const int c0 = cp[2 * b], c1 = cp[2 * b + 1];
    const float* P = pq + ((size_t)(e * 2) * 64 + c0) * 1024 + t * 8;
    const float* Q = pq + ((size_t)(e * 2 + 1) * 64 + c1) * 1024 + t * 8;
    const float* B = be + e * 1024 + t * 8;
#pragma unroll
    for (int i = 0; i < 8; ++i) {
      float v = P[i] + Q[i] + B[i];
      o[i] = f2bf(v > 0.f ? v : 0.f);
    }
    *(u16x8*)(Y + (size_t)b * 2048 + t * 8) = o;
  } else {
    const float* X = x2 + (size_t)b * 1024 + (size_t)(t - 128) * 8;
#pragma unroll
    for (int i = 0; i < 8; ++i) o[i] = f2bf(X[i]);
    *(u16x8*)(Y + (size_t)b * 2048 + 1024 + (size_t)(t - 128) * 8) = o;
  }
}

// ---------------- bf16 MFMA GEMM: C(MxN) = relu(A(MxK) @ BT(NxK)^T + bias) ---
// m97 structure + XOR bank-conflict swizzle + XCD supertile swizzle.
__global__ __launch_bounds__(256) void k_gemm(const u16* __restrict__ A,
                                              const u16* __restrict__ BT,
                                              const float* __restrict__ bias,
                                              u16* __restrict__ C, int M, int N, int K) {
  __shared__ u16 As[128 * 32];
  __shared__ u16 Bs[128 * 32];
  const int tid = threadIdx.x;
  const int lane = tid & 63;
  const int wave = tid >> 6;

  // XCD supertile swizzle: bid%8 = XCD (round-robin dispatch). Each XCD owns a
  // contiguous M-stripe (ny/8 rows x all N), snaking over N-panels of width 4.
  const int nx = gridDim.x, ny = gridDim.y;
  const int bid = blockIdx.y * nx + blockIdx.x;
  const int stripe = ny >> 3;                 // ny divisible by 8
  const int xcd = bid & 7;
  const int loc = bid >> 3;                   // [0, stripe*nx)
  const int panel = loc / (stripe * 4);
  const int rem = loc - panel * (stripe * 4);
  const int by = xcd * stripe + (rem >> 2);
  const int bx = panel * 4 + (rem & 3);
  const int tileN = bx * 128;
  const int tileM = by * 128;
  const int wm = wave & 1;
  const int wn = wave >> 1;

  f32x4v acc[4][4];
#pragma unroll
  for (int i = 0; i < 4; ++i)
#pragma unroll
    for (int j = 0; j < 4; ++j) acc[i][j] = (f32x4v){0.f, 0.f, 0.f, 0.f};

  // Staging: thread tid -> LDS row (tid>>2), physical 16B chunk (tid&3).
  // XOR swizzle: physical chunk (tid&3) holds LOGICAL k-chunk (tid&3)^((row>>1)&3).
  // This is a permutation within each 64B global segment -> coalescing intact.
  const int srow = tid >> 2;                          // 0..63
  const int scol = (((tid & 3) ^ ((tid >> 3) & 3))) * 8;  // logical k elems fetched
  const u16* aptr = A + (size_t)(tileM + srow) * K + scol;
  const u16* bptr = BT + (size_t)(tileN + srow) * K + scol;
  u16* asp = As + tid * 8;
  u16* bsp = Bs + tid * 8;

  // Fragment read: row r, logical k-chunk (lane>>4) lives at physical chunk
  // (lane>>4) ^ ((r>>1)&3). (r>>1)&3 == ((lane&15)>>1)&3 for all mi/ni offsets.
  const int s = ((lane & 15) >> 1) & 3;
  const int kph = (((lane >> 4) ^ s)) * 8;            // physical k elem offset
  const int am = wm * 64 + (lane & 15);
  const int bn = wn * 64 + (lane & 15);

  for (int k0 = 0; k0 < K; k0 += 32) {
    G2L16(aptr, asp);
    G2L16(aptr + (size_t)64 * K, asp + 2048);
    G2L16(bptr, bsp);
    G2L16(bptr + (size_t)64 * K, bsp + 2048);
    aptr += 32;
    bptr += 32;
    __syncthreads();

    bf16x8 af[4], bfr[4];
#pragma unroll
    for (int mi = 0; mi < 4; ++mi)
      af[mi] = *(const bf16x8*)(As + ((am + mi * 16) * 32 + kph));
#pragma unroll
    for (int ni = 0; ni < 4; ++ni)
      bfr[ni] = *(const bf16x8*)(Bs + ((bn + ni * 16) * 32 + kph));
#pragma unroll
    for (int mi = 0; mi < 4; ++mi)
#pragma unroll
      for (int ni = 0; ni < 4; ++ni)
        acc[mi][ni] = __builtin_amdgcn_mfma_f32_16x16x32_bf16(af[mi], bfr[ni], acc[mi][ni], 0, 0, 0);
    __syncthreads();
  }

  // C/D layout (m89-verified): col = lane&15, row = (lane>>4)*4 + reg
  const int crow = tileM + wm * 64 + (lane >> 4) * 4;
  const int ccol = tileN + wn * 64 + (lane & 15);
#pragma unroll
  for (int mi = 0; mi < 4; ++mi) {
#pragma unroll
    for (int ni = 0; ni < 4; ++ni) {
      const int c = ccol + ni * 16;
      const float bv = bias[c];
      const int r0 = crow + mi * 16;
#pragma unroll
      for (int r = 0; r < 4; ++r) {
        float v = acc[mi][ni][r] + bv;
        v = v > 0.f ? v : 0.f;
        C[(size_t)(r0 + r) * N + c] = f2bf(v);
      }
    }
  }
}

// ---------------- in-place layernorm over rows of bf16 H (cols = PER*256) ----
template <int PER>
__global__ __launch_bounds__(256) void k_ln(u16* __restrict__ H, const float* __restrict__ g,
                                            const float* __restrict__ bt) {
  const int cols = PER * 256;
  u16* row = H + (size_t)blockIdx.x * cols;
  const int t = threadIdx.x;
  float vals[PER];
  float s = 0.f, ss = 0.f;
#pragma unroll
  for (int j = 0; j < PER; j += 8) {
    u16x8 v = *(const u16x8*)(row + t * PER + j);
#pragma unroll
    for (int i = 0; i < 8; ++i) {
      float f = bf2f(v[i]);
      vals[j + i] = f;
      s += f;
      ss += f * f;
    }
  }
#pragma unroll
  for (int off = 32; off > 0; off >>= 1) {
    s += __shfl_down(s, off, 64);
    ss += __shfl_down(ss, off, 64);
  }
  __shared__ float red[8];
  const int lane = t & 63, wv = t >> 6;
  if (lane == 0) { red[wv] = s; red[4 + wv] = ss; }
  __syncthreads();
  if (t == 0) {
    float S = red[0] + red[1] + red[2] + red[3];
    float SS = red[4] + red[5] + red[6] + red[7];
    float m = S * (1.f / cols);
    float var = SS * (1.f / cols) - m * m;
    red[0] = m;
    red[1] = rsqrtf(var + 1e-5f);
  }
  __syncthreads();
  const float m = red[0], rs = red[1];
#pragma unroll
  for (int j = 0; j < PER; j += 8) {
    u16x8 o;
#pragma unroll
    for (int i = 0; i < 8; ++i) {
      int col = t * PER + j + i;
      o[i] = f2bf((vals[j + i] - m) * rs * g[col] + bt[col]);
    }
    *(u16x8*)(row + t * PER + j) = o;
  }
}

// ---------------- fused LN2 + final: out[b] = sigmoid(LN(H2[b,:]).W3 + b3) ---
__global__ __launch_bounds__(256) void k_ln_final(const u16* __restrict__ H2,
                                                  const float* __restrict__ g,
                                                  const float* __restrict__ bt,
                                                  const float* __restrict__ W3,
                                                  const float* __restrict__ b3,
                                                  float* __restrict__ out) {
  const int b = blockIdx.x, t = threadIdx.x;
  const u16* row = H2 + (size_t)b * 2048;
  float vals[8];
  float s = 0.f, ss = 0.f;
  {
    u16x8 v = *(const u16x8*)(row + t * 8);
#pragma unroll
    for (int i = 0; i < 8; ++i) {
      float f = bf2f(v[i]);
      vals[i] = f;
      s += f;
      ss += f * f;
    }
  }
#pragma unroll
  for (int off = 32; off > 0; off >>= 1) {
    s += __shfl_down(s, off, 64);
    ss += __shfl_down(ss, off, 64);
  }
  __shared__ float red[8];
  const int lane = t & 63, wv = t >> 6;
  if (lane == 0) { red[wv] = s; red[4 + wv] = ss; }
  __syncthreads();
  if (t == 0) {
    float S = red[0] + red[1] + red[2] + red[3];
    float SS = red[4] + red[5] + red[6] + red[7];
    float m = S * (1.f / 2048.f);
    float var = SS * (1.f / 2048.f) - m * m;
    red[0] = m;
    red[1] = rsqrtf(var + 1e-5f);
  }
  __syncthreads();
  const float m = red[0], rs = red[1];
  float dot = 0.f;
#pragma unroll
  for (int i = 0; i < 8; ++i) {
    int col = t * 8 + i;
    float h = (vals[i] - m) * rs * g[col] + bt[col];
    dot += h * W3[col];
  }
#pragma unroll
  for (int off = 32; off > 0; off >>= 1) dot += __shfl_down(dot, off, 64);
  __syncthreads();
  if (lane == 0) red[wv] = dot;
  __syncthreads();
  if (t == 0) {
    float S = red[0] + red[1] + red[2] + red[3] + b3[0];
    out[b] = 1.f / (1.f + expf(-S));
  }
}

extern "C" void kernel_launch(void* const* d_in, const int* in_sizes, int n_in,
                              void* d_out, int out_size, void* d_ws, size_t ws_size,
                              hipStream_t stream) {
  const float* x1 = (const float*)d_in[0];    // (1,64,1024)
  const float* x2 = (const float*)d_in[1];    // (8192,1024)
  const float* We = (const float*)d_in[2];    // (4,2048,1024)
  const float* be = (const float*)d_in[3];    // (4,1024)
  const float* W1 = (const float*)d_in[4];    // (2048,4096)
  const float* b1 = (const float*)d_in[5];
  const float* g1 = (const float*)d_in[6];
  const float* bt1 = (const float*)d_in[7];
  const float* W2 = (const float*)d_in[8];    // (4096,2048)
  const float* b2 = (const float*)d_in[9];
  const float* g2 = (const float*)d_in[10];
  const float* bt2 = (const float*)d_in[11];
  const float* W3 = (const float*)d_in[12];   // (2048,1)
  const float* b3 = (const float*)d_in[13];
  const int* cp = (const int*)d_in[14];       // (8192,2)
  const int* vis = (const int*)d_in[15];      // (8192,)
  float* out = (float*)d_out;

  char* ws = (char*)d_ws;
  u16* W1T = (u16*)(ws);                  // 4096x2048 bf16 = 16 MiB
  u16* W2T = (u16*)(ws + 16777216);       // 2048x4096 bf16 = 16 MiB
  u16* Y   = (u16*)(ws + 33554432);       // 8192x2048 bf16 = 32 MiB (reused as H2)
  u16* H1  = (u16*)(ws + 67108864);       // 8192x4096 bf16 = 64 MiB
  float* PQ = (float*)(ws + 134217728);   // 8x64x1024 fp32 = 2 MiB
  u16* H2 = Y;

  hipMemsetAsync(PQ, 0, 8 * 64 * 1024 * sizeof(float), stream);
  k_transpose2<<<16384, 256, 0, stream>>>(W1, W1T, W2, W2T);
  k_pq<<<dim3(16, 8, 8), 256, 0, stream>>>(x1, We, PQ);
  k_build_y<<<8192, 256, 0, stream>>>(PQ, x2, be, cp, vis, Y);
  k_gemm<<<dim3(4096 / 128, 8192 / 128), 256, 0, stream>>>(Y, W1T, b1, H1, 8192, 4096, 2048);
  k_ln<16><<<8192, 256, 0, stream>>>(H1, g1, bt1);
  k_gemm<<<dim3(2048 / 128, 8192 / 128), 256, 0, stream>>>(H1, W2T, b2, H2, 8192, 2048, 4096);
  k_ln_final<<<8192, 256, 0, stream>>>(H2, g2, bt2, W3, b3, out);
}

// Round 3
// 516.348 us; speedup vs baseline: 1.3075x; 1.3075x over previous
//
#include <hip/hip_runtime.h>

typedef unsigned short u16;
typedef __bf16 bf16x8 __attribute__((ext_vector_type(8)));
typedef float f32x4v __attribute__((ext_vector_type(4)));
typedef u16 u16x8 __attribute__((ext_vector_type(8)));

__device__ __forceinline__ u16 f2bf(float f) {
  union { float f; unsigned u; } v; v.f = f;
  unsigned r = v.u + 0x7fffu + ((v.u >> 16) & 1u);  // round-to-nearest-even
  return (u16)(r >> 16);
}
__device__ __forceinline__ float bf2f(u16 h) {
  union { unsigned u; float f; } v; v.u = ((unsigned)h) << 16;
  return v.f;
}

#define G2L16(g, l)                                                            \
  __builtin_amdgcn_global_load_lds((__attribute__((address_space(1))) void*)(g), \
                                   (__attribute__((address_space(3))) void*)(l), 16, 0, 0)

// ---------- merged transpose + fp32->bf16, 64x64 tiles, float4 loads --------
// W1 (2048x4096) -> W1T (4096x2048); W2 (4096x2048) -> W2T (2048x4096)
__global__ __launch_bounds__(256) void k_transpose2(const float* __restrict__ W1,
                                                    u16* __restrict__ W1T,
                                                    const float* __restrict__ W2,
                                                    u16* __restrict__ W2T) {
  __shared__ float tile[64][65];
  int bid = blockIdx.x;
  const float* in;
  u16* out;
  int R, C, bx, by;
  if (bid < 2048) {            // W1: 32 row-tiles x 64 col-tiles
    in = W1; out = W1T; R = 2048; C = 4096;
    bx = bid & 63; by = bid >> 6;
  } else {                     // W2: 64 row-tiles x 32 col-tiles
    bid -= 2048;
    in = W2; out = W2T; R = 4096; C = 2048;
    bx = bid & 31; by = bid >> 5;
  }
  const int c0 = bx * 64, r0 = by * 64;
  const int tc = (threadIdx.x & 15) * 4, tr = threadIdx.x >> 4;
#pragma unroll
  for (int i = 0; i < 4; ++i) {
    int r = tr + i * 16;
    f32x4v v = *(const f32x4v*)(in + (size_t)(r0 + r) * C + c0 + tc);
    tile[r][tc] = v[0]; tile[r][tc + 1] = v[1];
    tile[r][tc + 2] = v[2]; tile[r][tc + 3] = v[3];
  }
  __syncthreads();
  const int oc = threadIdx.x >> 2;        // output row (= input col) 0..63
  const int rb = (threadIdx.x & 3) * 16;  // 16 input rows each
  u16x8 o0, o1;
#pragma unroll
  for (int i = 0; i < 8; ++i) o0[i] = f2bf(tile[rb + i][oc]);
#pragma unroll
  for (int i = 0; i < 8; ++i) o1[i] = f2bf(tile[rb + 8 + i][oc]);
  *(u16x8*)(out + (size_t)(c0 + oc) * R + r0 + rb) = o0;
  *(u16x8*)(out + (size_t)(c0 + oc) * R + r0 + rb + 8) = o1;
}

// ---------------- PQ table (split-K, atomicAdd into zeroed PQ) ---------------
__global__ __launch_bounds__(256) void k_pq(const float* __restrict__ x1,
                                            const float* __restrict__ We,
                                            float* __restrict__ pq) {
  const int n0 = blockIdx.x * 64;
  const int ep = blockIdx.y;  // e*2+p
  const int e = ep >> 1, p = ep & 1;
  const int ks = blockIdx.z * 128;
  __shared__ float As[64][33];
  __shared__ float Bs[32][68];
  const int t = threadIdx.x;
  const int tx = t & 15, ty = t >> 4;
  float acc[4][4] = {};
  const float* wbase = We + (size_t)e * 2048 * 1024 + (size_t)p * 1024 * 1024;
  for (int k0 = ks; k0 < ks + 128; k0 += 32) {
#pragma unroll
    for (int i = 0; i < 8; ++i) {
      int idx = t + i * 256;
      As[idx >> 5][idx & 31] = x1[(size_t)(idx >> 5) * 1024 + k0 + (idx & 31)];
    }
#pragma unroll
    for (int i = 0; i < 8; ++i) {
      int idx = t + i * 256;
      Bs[idx >> 6][idx & 63] = wbase[(size_t)(k0 + (idx >> 6)) * 1024 + n0 + (idx & 63)];
    }
    __syncthreads();
#pragma unroll
    for (int kk = 0; kk < 32; ++kk) {
      float av[4];
#pragma unroll
      for (int i = 0; i < 4; ++i) av[i] = As[ty * 4 + i][kk];
      f32x4v bv = *(const f32x4v*)&Bs[kk][tx * 4];
#pragma unroll
      for (int i = 0; i < 4; ++i)
#pragma unroll
        for (int j = 0; j < 4; ++j) acc[i][j] += av[i] * bv[j];
    }
    __syncthreads();
  }
#pragma unroll
  for (int i = 0; i < 4; ++i) {
    float* dst = pq + ((size_t)ep * 64 + ty * 4 + i) * 1024 + n0 + tx * 4;
#pragma unroll
    for (int j = 0; j < 4; ++j) atomicAdd(&dst[j], acc[i][j]);
  }
}

// ---------------- build Y (8192 x 2048, bf16): [relu(P+Q+be) | x2] ----------
__global__ __launch_bounds__(256) void k_build_y(const float* __restrict__ pq,
                                                 const float* __restrict__ x2,
                                                 const float* __restrict__ be,
                                                 const int* __restrict__ cp,
                                                 const int* __restrict__ vis,
                                                 u16* __restrict__ Y) {
  const int b = blockIdx.x;
  const int t = threadIdx.x;
  const int e = vis[b];
  u16x8 o;
  if (t < 128) {
    const int c0 = cp[2 * b], c1 = cp[2 * b + 1];
    const float* P = pq + ((size_t)(e * 2) * 64 + c0) * 1024 + t * 8;
    const float* Q = pq + ((size_t)(e * 2 + 1) * 64 + c1) * 1024 + t * 8;
    const float* B = be + e * 1024 + t * 8;
#pragma unroll
    for (int i = 0; i < 8; ++i) {
      float v = P[i] + Q[i] + B[i];
      o[i] = f2bf(v > 0.f ? v : 0.f);
    }
    *(u16x8*)(Y + (size_t)b * 2048 + t * 8) = o;
  } else {
    const float* X = x2 + (size_t)b * 1024 + (size_t)(t - 128) * 8;
#pragma unroll
    for (int i = 0; i < 8; ++i) o[i] = f2bf(X[i]);
    *(u16x8*)(Y + (size_t)b * 2048 + 1024 + (size_t)(t - 128) * 8) = o;
  }
}

// ---------------- bf16 MFMA GEMM: C(MxN) = relu(A(MxK) @ BT(NxK)^T + bias) ---
// 128x128 tile, BK=64 (32 MFMA per barrier pair), XOR swizzle, XCD supertile.
__global__ __launch_bounds__(256, 3) void k_gemm(const u16* __restrict__ A,
                                                 const u16* __restrict__ BT,
                                                 const float* __restrict__ bias,
                                                 u16* __restrict__ C, int M, int N, int K) {
  __shared__ u16 As[128 * 64];   // 16 KB
  __shared__ u16 Bs[128 * 64];   // 16 KB
  const int tid = threadIdx.x;
  const int lane = tid & 63;
  const int wave = tid >> 6;

  // XCD supertile swizzle (round-robin dispatch: bid%8 = XCD).
  const int nx = gridDim.x, ny = gridDim.y;
  const int bid = blockIdx.y * nx + blockIdx.x;
  const int stripe = ny >> 3;
  const int xcd = bid & 7;
  const int loc = bid >> 3;
  const int panel = loc / (stripe * 4);
  const int rem = loc - panel * (stripe * 4);
  const int by = xcd * stripe + (rem >> 2);
  const int bx = panel * 4 + (rem & 3);
  const int tileN = bx * 128;
  const int tileM = by * 128;
  const int wm = wave & 1;
  const int wn = wave >> 1;

  f32x4v acc[4][4];
#pragma unroll
  for (int i = 0; i < 4; ++i)
#pragma unroll
    for (int j = 0; j < 4; ++j) acc[i][j] = (f32x4v){0.f, 0.f, 0.f, 0.f};

  // Staging: row = tid>>3 (0..31), physical 16B chunk = tid&7 (8 chunks/row).
  // XOR swizzle: phys chunk holds logical chunk (tid&7)^(row&7) -> within-row
  // permutation of each 128B global segment (coalescing intact).
  const int srow = tid >> 3;
  const int lchunk = (tid & 7) ^ (srow & 7);
  const u16* aptr = A + (size_t)(tileM + srow) * K + lchunk * 8;
  const u16* bptr = BT + (size_t)(tileN + srow) * K + lchunk * 8;
  u16* asp = As + tid * 8;   // byte offset tid*16: wave-uniform base + lane*16
  u16* bsp = Bs + tid * 8;

  // Fragment reads: row r needs logical chunk c at phys c^(r&7); r&7 == lane&7
  // for all mi offsets (multiples of 16). Within any 16 consecutive lanes all
  // 8 bank-quads are hit exactly 2x -> conflict-free (validated round 2).
  const int s = lane & 7;
  const int kp0 = ((lane >> 4) ^ s) * 8;  // K-step 0 chunk (logical lane>>4)
  const int kp1 = kp0 ^ 32;               // K-step 1 chunk (logical +4)
  const int am = wm * 64 + (lane & 15);
  const int bn = wn * 64 + (lane & 15);

  for (int k0 = 0; k0 < K; k0 += 64) {
    G2L16(aptr, asp);
    G2L16(aptr + (size_t)32 * K, asp + 2048);
    G2L16(aptr + (size_t)64 * K, asp + 4096);
    G2L16(aptr + (size_t)96 * K, asp + 6144);
    G2L16(bptr, bsp);
    G2L16(bptr + (size_t)32 * K, bsp + 2048);
    G2L16(bptr + (size_t)64 * K, bsp + 4096);
    G2L16(bptr + (size_t)96 * K, bsp + 6144);
    aptr += 64;
    bptr += 64;
    __syncthreads();

    bf16x8 af[4], bfr[4];
    // K-step 0 (k = k0..k0+31)
#pragma unroll
    for (int mi = 0; mi < 4; ++mi)
      af[mi] = *(const bf16x8*)(As + (am + mi * 16) * 64 + kp0);
#pragma unroll
    for (int ni = 0; ni < 4; ++ni)
      bfr[ni] = *(const bf16x8*)(Bs + (bn + ni * 16) * 64 + kp0);
#pragma unroll
    for (int mi = 0; mi < 4; ++mi)
#pragma unroll
      for (int ni = 0; ni < 4; ++ni)
        acc[mi][ni] = __builtin_amdgcn_mfma_f32_16x16x32_bf16(af[mi], bfr[ni], acc[mi][ni], 0, 0, 0);
    // K-step 1 (k = k0+32..k0+63)
#pragma unroll
    for (int mi = 0; mi < 4; ++mi)
      af[mi] = *(const bf16x8*)(As + (am + mi * 16) * 64 + kp1);
#pragma unroll
    for (int ni = 0; ni < 4; ++ni)
      bfr[ni] = *(const bf16x8*)(Bs + (bn + ni * 16) * 64 + kp1);
#pragma unroll
    for (int mi = 0; mi < 4; ++mi)
#pragma unroll
      for (int ni = 0; ni < 4; ++ni)
        acc[mi][ni] = __builtin_amdgcn_mfma_f32_16x16x32_bf16(af[mi], bfr[ni], acc[mi][ni], 0, 0, 0);
    __syncthreads();
  }

  // C/D layout (m89-verified): col = lane&15, row = (lane>>4)*4 + reg
  const int crow = tileM + wm * 64 + (lane >> 4) * 4;
  const int ccol = tileN + wn * 64 + (lane & 15);
#pragma unroll
  for (int mi = 0; mi < 4; ++mi) {
#pragma unroll
    for (int ni = 0; ni < 4; ++ni) {
      const int c = ccol + ni * 16;
      const float bv = bias[c];
      const int r0 = crow + mi * 16;
#pragma unroll
      for (int r = 0; r < 4; ++r) {
        float v = acc[mi][ni][r] + bv;
        v = v > 0.f ? v : 0.f;
        C[(size_t)(r0 + r) * N + c] = f2bf(v);
      }
    }
  }
}

// -------- in-place layernorm, fully coalesced (cols = CHUNKS*2048) ----------
template <int CHUNKS>
__global__ __launch_bounds__(256) void k_ln(u16* __restrict__ H, const float* __restrict__ g,
                                            const float* __restrict__ bt) {
  const int cols = CHUNKS * 2048;
  u16* row = H + (size_t)blockIdx.x * cols;
  const int t = threadIdx.x;
  float vals[CHUNKS][8];
  float s = 0.f, ss = 0.f;
#pragma unroll
  for (int j = 0; j < CHUNKS; ++j) {
    u16x8 v = *(const u16x8*)(row + j * 2048 + t * 8);  // lanes consecutive 16B
#pragma unroll
    for (int i = 0; i < 8; ++i) {
      float f = bf2f(v[i]);
      vals[j][i] = f;
      s += f;
      ss += f * f;
    }
  }
#pragma unroll
  for (int off = 32; off > 0; off >>= 1) {
    s += __shfl_down(s, off, 64);
    ss += __shfl_down(ss, off, 64);
  }
  __shared__ float red[8];
  const int lane = t & 63, wv = t >> 6;
  if (lane == 0) { red[wv] = s; red[4 + wv] = ss; }
  __syncthreads();
  if (t == 0) {
    float S = red[0] + red[1] + red[2] + red[3];
    float SS = red[4] + red[5] + red[6] + red[7];
    float m = S * (1.f / cols);
    float var = SS * (1.f / cols) - m * m;
    red[0] = m;
    red[1] = rsqrtf(var + 1e-5f);
  }
  __syncthreads();
  const float m = red[0], rs = red[1];
#pragma unroll
  for (int j = 0; j < CHUNKS; ++j) {
    u16x8 o;
#pragma unroll
    for (int i = 0; i < 8; ++i) {
      int col = j * 2048 + t * 8 + i;
      o[i] = f2bf((vals[j][i] - m) * rs * g[col] + bt[col]);
    }
    *(u16x8*)(row + j * 2048 + t * 8) = o;
  }
}

// ---------------- fused LN2 + final: out[b] = sigmoid(LN(H2[b,:]).W3 + b3) ---
__global__ __launch_bounds__(256) void k_ln_final(const u16* __restrict__ H2,
                                                  const float* __restrict__ g,
                                                  const float* __restrict__ bt,
                                                  const float* __restrict__ W3,
                                                  const float* __restrict__ b3,
                                                  float* __restrict__ out) {
  const int b = blockIdx.x, t = threadIdx.x;
  const u16* row = H2 + (size_t)b * 2048;
  float vals[8];
  float s = 0.f, ss = 0.f;
  {
    u16x8 v = *(const u16x8*)(row + t * 8);
#pragma unroll
    for (int i = 0; i < 8; ++i) {
      float f = bf2f(v[i]);
      vals[i] = f;
      s += f;
      ss += f * f;
    }
  }
#pragma unroll
  for (int off = 32; off > 0; off >>= 1) {
    s += __shfl_down(s, off, 64);
    ss += __shfl_down(ss, off, 64);
  }
  __shared__ float red[8];
  const int lane = t & 63, wv = t >> 6;
  if (lane == 0) { red[wv] = s; red[4 + wv] = ss; }
  __syncthreads();
  if (t == 0) {
    float S = red[0] + red[1] + red[2] + red[3];
    float SS = red[4] + red[5] + red[6] + red[7];
    float m = S * (1.f / 2048.f);
    float var = SS * (1.f / 2048.f) - m * m;
    red[0] = m;
    red[1] = rsqrtf(var + 1e-5f);
  }
  __syncthreads();
  const float m = red[0], rs = red[1];
  float dot = 0.f;
#pragma unroll
  for (int i = 0; i < 8; ++i) {
    int col = t * 8 + i;
    float h = (vals[i] - m) * rs * g[col] + bt[col];
    dot += h * W3[col];
  }
#pragma unroll
  for (int off = 32; off > 0; off >>= 1) dot += __shfl_down(dot, off, 64);
  __syncthreads();
  if (lane == 0) red[wv] = dot;
  __syncthreads();
  if (t == 0) {
    float S = red[0] + red[1] + red[2] + red[3] + b3[0];
    out[b] = 1.f / (1.f + expf(-S));
  }
}

extern "C" void kernel_launch(void* const* d_in, const int* in_sizes, int n_in,
                              void* d_out, int out_size, void* d_ws, size_t ws_size,
                              hipStream_t stream) {
  const float* x1 = (const float*)d_in[0];
  const float* x2 = (const float*)d_in[1];
  const float* We = (const float*)d_in[2];
  const float* be = (const float*)d_in[3];
  const float* W1 = (const float*)d_in[4];
  const float* b1 = (const float*)d_in[5];
  const float* g1 = (const float*)d_in[6];
  const float* bt1 = (const float*)d_in[7];
  const float* W2 = (const float*)d_in[8];
  const float* b2 = (const float*)d_in[9];
  const float* g2 = (const float*)d_in[10];
  const float* bt2 = (const float*)d_in[11];
  const float* W3 = (const float*)d_in[12];
  const float* b3 = (const float*)d_in[13];
  const int* cp = (const int*)d_in[14];
  const int* vis = (const int*)d_in[15];
  float* out = (float*)d_out;

  char* ws = (char*)d_ws;
  u16* W1T = (u16*)(ws);                  // 4096x2048 bf16 = 16 MiB
  u16* W2T = (u16*)(ws + 16777216);       // 2048x4096 bf16 = 16 MiB
  u16* Y   = (u16*)(ws + 33554432);       // 8192x2048 bf16 = 32 MiB (reused as H2)
  u16* H1  = (u16*)(ws + 67108864);       // 8192x4096 bf16 = 64 MiB
  float* PQ = (float*)(ws + 134217728);   // 8x64x1024 fp32 = 2 MiB
  u16* H2 = Y;

  hipMemsetAsync(PQ, 0, 8 * 64 * 1024 * sizeof(float), stream);
  k_transpose2<<<4096, 256, 0, stream>>>(W1, W1T, W2, W2T);
  k_pq<<<dim3(16, 8, 8), 256, 0, stream>>>(x1, We, PQ);
  k_build_y<<<8192, 256, 0, stream>>>(PQ, x2, be, cp, vis, Y);
  k_gemm<<<dim3(4096 / 128, 8192 / 128), 256, 0, stream>>>(Y, W1T, b1, H1, 8192, 4096, 2048);
  k_ln<2><<<8192, 256, 0, stream>>>(H1, g1, bt1);
  k_gemm<<<dim3(2048 / 128, 8192 / 128), 256, 0, stream>>>(H1, W2T, b2, H2, 8192, 2048, 4096);
  k_ln_final<<<8192, 256, 0, stream>>>(H2, g2, bt2, W3, b3, out);
}

// Round 4
// 491.674 us; speedup vs baseline: 1.3731x; 1.0502x over previous
//
#include <hip/hip_runtime.h>

typedef unsigned short u16;
typedef __bf16 bf16x8 __attribute__((ext_vector_type(8)));
typedef float f32x4v __attribute__((ext_vector_type(4)));
typedef u16 u16x8 __attribute__((ext_vector_type(8)));

__device__ __forceinline__ u16 f2bf(float f) {
  union { float f; unsigned u; } v; v.f = f;
  unsigned r = v.u + 0x7fffu + ((v.u >> 16) & 1u);  // round-to-nearest-even
  return (u16)(r >> 16);
}
__device__ __forceinline__ float bf2f(u16 h) {
  union { unsigned u; float f; } v; v.u = ((unsigned)h) << 16;
  return v.f;
}

#define G2L16(g, l)                                                            \
  __builtin_amdgcn_global_load_lds((__attribute__((address_space(1))) void*)(g), \
                                   (__attribute__((address_space(3))) void*)(l), 16, 0, 0)

// ---------- merged transpose + fp32->bf16, 64x64 tiles, float4 loads --------
// W1 (2048x4096) -> W1T (4096x2048); W2 (4096x2048) -> W2gT (2048x4096) with
// g1[k] folded in (W2gT[n][k] = g1[k]*W2[k][n]).
__global__ __launch_bounds__(256) void k_transpose2(const float* __restrict__ W1,
                                                    u16* __restrict__ W1T,
                                                    const float* __restrict__ W2,
                                                    u16* __restrict__ W2gT,
                                                    const float* __restrict__ g1) {
  __shared__ float tile[64][65];
  int bid = blockIdx.x;
  const float* in;
  u16* out;
  int R, C, bx, by, fold;
  if (bid < 2048) {            // W1: 32 row-tiles x 64 col-tiles
    in = W1; out = W1T; R = 2048; C = 4096; fold = 0;
    bx = bid & 63; by = bid >> 6;
  } else {                     // W2: 64 row-tiles x 32 col-tiles
    bid -= 2048;
    in = W2; out = W2gT; R = 4096; C = 2048; fold = 1;
    bx = bid & 31; by = bid >> 5;
  }
  const int c0 = bx * 64, r0 = by * 64;
  const int tc = (threadIdx.x & 15) * 4, tr = threadIdx.x >> 4;
#pragma unroll
  for (int i = 0; i < 4; ++i) {
    int r = tr + i * 16;
    f32x4v v = *(const f32x4v*)(in + (size_t)(r0 + r) * C + c0 + tc);
    tile[r][tc] = v[0]; tile[r][tc + 1] = v[1];
    tile[r][tc + 2] = v[2]; tile[r][tc + 3] = v[3];
  }
  __syncthreads();
  const int oc = threadIdx.x >> 2;        // output row (= input col) 0..63
  const int rb = (threadIdx.x & 3) * 16;  // 16 input rows each
  float gv[16];
#pragma unroll
  for (int i = 0; i < 16; ++i) gv[i] = fold ? g1[r0 + rb + i] : 1.f;
  u16x8 o0, o1;
#pragma unroll
  for (int i = 0; i < 8; ++i) o0[i] = f2bf(tile[rb + i][oc] * gv[i]);
#pragma unroll
  for (int i = 0; i < 8; ++i) o1[i] = f2bf(tile[rb + 8 + i][oc] * gv[8 + i]);
  *(u16x8*)(out + (size_t)(c0 + oc) * R + r0 + rb) = o0;
  *(u16x8*)(out + (size_t)(c0 + oc) * R + r0 + rb + 8) = o1;
}

// -------- PQ table, split-K=2 into separate partial buffers (no atomics) ----
// pqz[(e*2+p)][c][n] = sum_{k in z-half} x1[c][k] * We[e][p*1024+k][n]
__global__ __launch_bounds__(256) void k_pq(const float* __restrict__ x1,
                                            const float* __restrict__ We,
                                            float* __restrict__ pq0,
                                            float* __restrict__ pq1) {
  const int n0 = blockIdx.x * 64;
  const int ep = blockIdx.y;  // e*2+p
  const int e = ep >> 1, p = ep & 1;
  const int ks = blockIdx.z * 512;
  float* pq = blockIdx.z ? pq1 : pq0;
  __shared__ float As[64][33];
  __shared__ float Bs[32][68];
  const int t = threadIdx.x;
  const int tx = t & 15, ty = t >> 4;
  float acc[4][4] = {};
  const float* wbase = We + (size_t)e * 2048 * 1024 + (size_t)p * 1024 * 1024;
  for (int k0 = ks; k0 < ks + 512; k0 += 32) {
#pragma unroll
    for (int i = 0; i < 8; ++i) {
      int idx = t + i * 256;
      As[idx >> 5][idx & 31] = x1[(size_t)(idx >> 5) * 1024 + k0 + (idx & 31)];
    }
#pragma unroll
    for (int i = 0; i < 8; ++i) {
      int idx = t + i * 256;
      Bs[idx >> 6][idx & 63] = wbase[(size_t)(k0 + (idx >> 6)) * 1024 + n0 + (idx & 63)];
    }
    __syncthreads();
#pragma unroll
    for (int kk = 0; kk < 32; ++kk) {
      float av[4];
#pragma unroll
      for (int i = 0; i < 4; ++i) av[i] = As[ty * 4 + i][kk];
      f32x4v bv = *(const f32x4v*)&Bs[kk][tx * 4];
#pragma unroll
      for (int i = 0; i < 4; ++i)
#pragma unroll
        for (int j = 0; j < 4; ++j) acc[i][j] += av[i] * bv[j];
    }
    __syncthreads();
  }
#pragma unroll
  for (int i = 0; i < 4; ++i) {
    float* dst = pq + ((size_t)ep * 64 + ty * 4 + i) * 1024 + n0 + tx * 4;
#pragma unroll
    for (int j = 0; j < 4; ++j) dst[j] = acc[i][j];
  }
}

// ---- s1[n] = sum_k g1[k]*W2[k][n];  c1b[n] = sum_k bt1[k]*W2[k][n] + b2[n] --
__global__ __launch_bounds__(256) void k_w2vec(const float* __restrict__ W2,
                                               const float* __restrict__ g1,
                                               const float* __restrict__ bt1,
                                               const float* __restrict__ b2,
                                               float* __restrict__ s1,
                                               float* __restrict__ c1b) {
  const int n = blockIdx.x * 256 + threadIdx.x;
  const int ks = blockIdx.y * 256;
  float s = 0.f, c = 0.f;
  for (int k = ks; k < ks + 256; ++k) {
    float w = W2[(size_t)k * 2048 + n];
    s += g1[k] * w;
    c += bt1[k] * w;
  }
  if (blockIdx.y == 0) c += b2[n];
  atomicAdd(&s1[n], s);
  atomicAdd(&c1b[n], c);
}

// ---------------- build Y (8192 x 2048, bf16): [relu(P+Q+be) | x2] ----------
__global__ __launch_bounds__(256) void k_build_y(const float* __restrict__ pq0,
                                                 const float* __restrict__ pq1,
                                                 const float* __restrict__ x2,
                                                 const float* __restrict__ be,
                                                 const int* __restrict__ cp,
                                                 const int* __restrict__ vis,
                                                 u16* __restrict__ Y) {
  const int b = blockIdx.x;
  const int t = threadIdx.x;
  const int e = vis[b];
  u16x8 o;
  if (t < 128) {
    const int c0 = cp[2 * b], c1 = cp[2 * b + 1];
    const size_t po = ((size_t)(e * 2) * 64 + c0) * 1024 + t * 8;
    const size_t qo = ((size_t)(e * 2 + 1) * 64 + c1) * 1024 + t * 8;
    const float* B = be + e * 1024 + t * 8;
#pragma unroll
    for (int i = 0; i < 8; ++i) {
      float v = pq0[po + i] + pq1[po + i] + pq0[qo + i] + pq1[qo + i] + B[i];
      o[i] = f2bf(v > 0.f ? v : 0.f);
    }
    *(u16x8*)(Y + (size_t)b * 2048 + t * 8) = o;
  } else {
    const float* X = x2 + (size_t)b * 1024 + (size_t)(t - 128) * 8;
#pragma unroll
    for (int i = 0; i < 8; ++i) o[i] = f2bf(X[i]);
    *(u16x8*)(Y + (size_t)b * 2048 + 1024 + (size_t)(t - 128) * 8) = o;
  }
}

// ---------------- bf16 MFMA GEMM: C(MxN) = epilogue(A(MxK) @ BT(NxK)^T) -----
// 128x128 tile, BK=64, XOR swizzle, XCD supertile. MODE 0: relu(acc+bias).
// MODE 1 (LN1 folded): relu(rs_r*acc - rs_r*m_r*s1[c] + c1b[c]).
template <int MODE>
__global__ __launch_bounds__(256, 4) void k_gemm(const u16* __restrict__ A,
                                                 const u16* __restrict__ BT,
                                                 const float* __restrict__ bias,
                                                 const float2* __restrict__ stats,
                                                 const float* __restrict__ s1,
                                                 const float* __restrict__ c1b,
                                                 u16* __restrict__ C, int M, int N, int K) {
  __shared__ u16 As[128 * 64];   // 16 KB
  __shared__ u16 Bs[128 * 64];   // 16 KB
  const int tid = threadIdx.x;
  const int lane = tid & 63;
  const int wave = tid >> 6;

  // XCD supertile swizzle (round-robin dispatch: bid%8 = XCD).
  const int nx = gridDim.x, ny = gridDim.y;
  const int bid = blockIdx.y * nx + blockIdx.x;
  const int stripe = ny >> 3;
  const int xcd = bid & 7;
  const int loc = bid >> 3;
  const int panel = loc / (stripe * 4);
  const int rem = loc - panel * (stripe * 4);
  const int by = xcd * stripe + (rem >> 2);
  const int bx = panel * 4 + (rem & 3);
  const int tileN = bx * 128;
  const int tileM = by * 128;
  const int wm = wave & 1;
  const int wn = wave >> 1;

  f32x4v acc[4][4];
#pragma unroll
  for (int i = 0; i < 4; ++i)
#pragma unroll
    for (int j = 0; j < 4; ++j) acc[i][j] = (f32x4v){0.f, 0.f, 0.f, 0.f};

  // Staging: row = tid>>3 (0..31), physical 16B chunk = tid&7.
  // XOR swizzle: phys chunk holds logical chunk (tid&7)^(row&7).
  const int srow = tid >> 3;
  const int lchunk = (tid & 7) ^ (srow & 7);
  const u16* aptr = A + (size_t)(tileM + srow) * K + lchunk * 8;
  const u16* bptr = BT + (size_t)(tileN + srow) * K + lchunk * 8;
  u16* asp = As + tid * 8;
  u16* bsp = Bs + tid * 8;

  // Fragment reads: row r, logical chunk c at phys c^(r&7); conflict-free.
  const int s = lane & 7;
  const int kp0 = ((lane >> 4) ^ s) * 8;
  const int kp1 = kp0 ^ 32;
  const int am = wm * 64 + (lane & 15);
  const int bn = wn * 64 + (lane & 15);

  for (int k0 = 0; k0 < K; k0 += 64) {
    G2L16(aptr, asp);
    G2L16(aptr + (size_t)32 * K, asp + 2048);
    G2L16(aptr + (size_t)64 * K, asp + 4096);
    G2L16(aptr + (size_t)96 * K, asp + 6144);
    G2L16(bptr, bsp);
    G2L16(bptr + (size_t)32 * K, bsp + 2048);
    G2L16(bptr + (size_t)64 * K, bsp + 4096);
    G2L16(bptr + (size_t)96 * K, bsp + 6144);
    aptr += 64;
    bptr += 64;
    __syncthreads();

    bf16x8 af[4], bfr[4];
#pragma unroll
    for (int mi = 0; mi < 4; ++mi)
      af[mi] = *(const bf16x8*)(As + (am + mi * 16) * 64 + kp0);
#pragma unroll
    for (int ni = 0; ni < 4; ++ni)
      bfr[ni] = *(const bf16x8*)(Bs + (bn + ni * 16) * 64 + kp0);
#pragma unroll
    for (int mi = 0; mi < 4; ++mi)
#pragma unroll
      for (int ni = 0; ni < 4; ++ni)
        acc[mi][ni] = __builtin_amdgcn_mfma_f32_16x16x32_bf16(af[mi], bfr[ni], acc[mi][ni], 0, 0, 0);
#pragma unroll
    for (int mi = 0; mi < 4; ++mi)
      af[mi] = *(const bf16x8*)(As + (am + mi * 16) * 64 + kp1);
#pragma unroll
    for (int ni = 0; ni < 4; ++ni)
      bfr[ni] = *(const bf16x8*)(Bs + (bn + ni * 16) * 64 + kp1);
#pragma unroll
    for (int mi = 0; mi < 4; ++mi)
#pragma unroll
      for (int ni = 0; ni < 4; ++ni)
        acc[mi][ni] = __builtin_amdgcn_mfma_f32_16x16x32_bf16(af[mi], bfr[ni], acc[mi][ni], 0, 0, 0);
    __syncthreads();
  }

  // C/D layout (m89-verified): col = lane&15, row = (lane>>4)*4 + reg
  const int crow = tileM + wm * 64 + (lane >> 4) * 4;
  const int ccol = tileN + wn * 64 + (lane & 15);
  float cv0[4], cv1[4];
#pragma unroll
  for (int ni = 0; ni < 4; ++ni) {
    const int c = ccol + ni * 16;
    if (MODE == 0) {
      cv0[ni] = bias[c];
    } else {
      cv0[ni] = s1[c];
      cv1[ni] = c1b[c];
    }
  }
#pragma unroll
  for (int mi = 0; mi < 4; ++mi) {
#pragma unroll
    for (int r = 0; r < 4; ++r) {
      const int row = crow + mi * 16 + r;
      float m = 0.f, rs = 0.f;
      if (MODE == 1) {
        float2 st = stats[row];
        m = st.x; rs = st.y;
      }
#pragma unroll
      for (int ni = 0; ni < 4; ++ni) {
        float v;
        if (MODE == 0)
          v = acc[mi][ni][r] + cv0[ni];
        else
          v = rs * acc[mi][ni][r] - rs * m * cv0[ni] + cv1[ni];
        v = v > 0.f ? v : 0.f;
        C[(size_t)row * N + ccol + ni * 16] = f2bf(v);
      }
    }
  }
}

// -------- per-row mean/rsqrt(var) of H1 (8192 x 4096 bf16) ------------------
__global__ __launch_bounds__(256) void k_stats(const u16* __restrict__ H1,
                                               float2* __restrict__ stats) {
  const u16* row = H1 + (size_t)blockIdx.x * 4096;
  const int t = threadIdx.x;
  float s = 0.f, ss = 0.f;
#pragma unroll
  for (int j = 0; j < 2; ++j) {
    u16x8 v = *(const u16x8*)(row + j * 2048 + t * 8);
#pragma unroll
    for (int i = 0; i < 8; ++i) {
      float f = bf2f(v[i]);
      s += f;
      ss += f * f;
    }
  }
#pragma unroll
  for (int off = 32; off > 0; off >>= 1) {
    s += __shfl_down(s, off, 64);
    ss += __shfl_down(ss, off, 64);
  }
  __shared__ float red[8];
  const int lane = t & 63, wv = t >> 6;
  if (lane == 0) { red[wv] = s; red[4 + wv] = ss; }
  __syncthreads();
  if (t == 0) {
    float S = red[0] + red[1] + red[2] + red[3];
    float SS = red[4] + red[5] + red[6] + red[7];
    float m = S * (1.f / 4096.f);
    float var = SS * (1.f / 4096.f) - m * m;
    stats[blockIdx.x] = make_float2(m, rsqrtf(var + 1e-5f));
  }
}

// ---------------- fused LN2 + final: out[b] = sigmoid(LN(H2[b,:]).W3 + b3) ---
__global__ __launch_bounds__(256) void k_ln_final(const u16* __restrict__ H2,
                                                  const float* __restrict__ g,
                                                  const float* __restrict__ bt,
                                                  const float* __restrict__ W3,
                                                  const float* __restrict__ b3,
                                                  float* __restrict__ out) {
  const int b = blockIdx.x, t = threadIdx.x;
  const u16* row = H2 + (size_t)b * 2048;
  float vals[8];
  float s = 0.f, ss = 0.f;
  {
    u16x8 v = *(const u16x8*)(row + t * 8);
#pragma unroll
    for (int i = 0; i < 8; ++i) {
      float f = bf2f(v[i]);
      vals[i] = f;
      s += f;
      ss += f * f;
    }
  }
#pragma unroll
  for (int off = 32; off > 0; off >>= 1) {
    s += __shfl_down(s, off, 64);
    ss += __shfl_down(ss, off, 64);
  }
  __shared__ float red[8];
  const int lane = t & 63, wv = t >> 6;
  if (lane == 0) { red[wv] = s; red[4 + wv] = ss; }
  __syncthreads();
  if (t == 0) {
    float S = red[0] + red[1] + red[2] + red[3];
    float SS = red[4] + red[5] + red[6] + red[7];
    float m = S * (1.f / 2048.f);
    float var = SS * (1.f / 2048.f) - m * m;
    red[0] = m;
    red[1] = rsqrtf(var + 1e-5f);
  }
  __syncthreads();
  const float m = red[0], rs = red[1];
  float dot = 0.f;
#pragma unroll
  for (int i = 0; i < 8; ++i) {
    int col = t * 8 + i;
    float h = (vals[i] - m) * rs * g[col] + bt[col];
    dot += h * W3[col];
  }
#pragma unroll
  for (int off = 32; off > 0; off >>= 1) dot += __shfl_down(dot, off, 64);
  __syncthreads();
  if (lane == 0) red[wv] = dot;
  __syncthreads();
  if (t == 0) {
    float S = red[0] + red[1] + red[2] + red[3] + b3[0];
    out[b] = 1.f / (1.f + expf(-S));
  }
}

extern "C" void kernel_launch(void* const* d_in, const int* in_sizes, int n_in,
                              void* d_out, int out_size, void* d_ws, size_t ws_size,
                              hipStream_t stream) {
  const float* x1 = (const float*)d_in[0];
  const float* x2 = (const float*)d_in[1];
  const float* We = (const float*)d_in[2];
  const float* be = (const float*)d_in[3];
  const float* W1 = (const float*)d_in[4];
  const float* b1 = (const float*)d_in[5];
  const float* g1 = (const float*)d_in[6];
  const float* bt1 = (const float*)d_in[7];
  const float* W2 = (const float*)d_in[8];
  const float* b2 = (const float*)d_in[9];
  const float* g2 = (const float*)d_in[10];
  const float* bt2 = (const float*)d_in[11];
  const float* W3 = (const float*)d_in[12];
  const float* b3 = (const float*)d_in[13];
  const int* cp = (const int*)d_in[14];
  const int* vis = (const int*)d_in[15];
  float* out = (float*)d_out;

  char* ws = (char*)d_ws;
  u16* W1T  = (u16*)(ws);                  // 4096x2048 bf16 = 16 MiB
  u16* W2gT = (u16*)(ws + 16777216);       // 2048x4096 bf16 = 16 MiB
  u16* Y    = (u16*)(ws + 33554432);       // 8192x2048 bf16 = 32 MiB (reused as H2)
  u16* H1   = (u16*)(ws + 67108864);       // 8192x4096 bf16 = 64 MiB
  float* PQ0 = (float*)(ws + 134217728);   // 8x64x1024 fp32 = 2 MiB
  float* PQ1 = (float*)(ws + 136314880);   // 2 MiB
  float2* stats = (float2*)(ws + 138412032);  // 8192 float2 = 64 KiB
  float* s1  = (float*)(ws + 138477568);   // 2048 f32 = 8 KiB
  float* c1b = (float*)(ws + 138485760);   // 2048 f32 = 8 KiB
  u16* H2 = Y;

  hipMemsetAsync(s1, 0, 2 * 2048 * sizeof(float), stream);  // s1 + c1b
  k_transpose2<<<4096, 256, 0, stream>>>(W1, W1T, W2, W2gT, g1);
  k_pq<<<dim3(16, 8, 2), 256, 0, stream>>>(x1, We, PQ0, PQ1);
  k_w2vec<<<dim3(8, 16), 256, 0, stream>>>(W2, g1, bt1, b2, s1, c1b);
  k_build_y<<<8192, 256, 0, stream>>>(PQ0, PQ1, x2, be, cp, vis, Y);
  k_gemm<0><<<dim3(4096 / 128, 8192 / 128), 256, 0, stream>>>(
      Y, W1T, b1, nullptr, nullptr, nullptr, H1, 8192, 4096, 2048);
  k_stats<<<8192, 256, 0, stream>>>(H1, stats);
  k_gemm<1><<<dim3(2048 / 128, 8192 / 128), 256, 0, stream>>>(
      H1, W2gT, nullptr, stats, s1, c1b, H2, 8192, 2048, 4096);
  k_ln_final<<<8192, 256, 0, stream>>>(H2, g2, bt2, W3, b3, out);
}